// Round 20
// baseline (41.941 us; speedup 1.0000x reference)
//
#include <hip/hip_runtime.h>

// B=256, T=256, D=384, HD=64
typedef __attribute__((ext_vector_type(8))) short bf16x8;
typedef __attribute__((ext_vector_type(4))) float f32x4;

__device__ inline unsigned short f2bf(float f) {
    unsigned u = __float_as_uint(f);
    return (unsigned short)((u + 0x7fffu + ((u >> 16) & 1u)) >> 16);
}
// HW packed f32x2 -> bf16x2 convert (RNE, same rounding as f2bf).
// Non-volatile: pure value op, scheduler may move/CSE it.
__device__ inline unsigned pkbf(float lo, float hi) {
    unsigned r;
    asm("v_cvt_pk_bf16_f32 %0, %1, %2" : "=v"(r) : "v"(lo), "v"(hi));
    return r;
}
__device__ inline void gload16(const void* g, void* l) {
    __builtin_amdgcn_global_load_lds(
        (const __attribute__((address_space(1))) unsigned*)g,
        (__attribute__((address_space(3))) unsigned*)l, 16, 0, 0);
}

// ---------------------------------------------------------------------------
// Kernel 0 (R7/R9-verified): W = [Wq;Wk;Wv] -> bf16 frag-major pre-swizzled:
//   Wp[kc*6144 + (((g*192 + col) ^ g) << 3) + kl] = W[col][kc*32 + g*8 + kl]
// ---------------------------------------------------------------------------
__global__ void wconv(const float* __restrict__ Wq, const float* __restrict__ Wk,
                      const float* __restrict__ Wv, short* __restrict__ Wp) {
    int i = blockIdx.x * 256 + threadIdx.x;
    if (i >= 192 * 384) return;
    int col = i / 384;
    int k   = i - col * 384;
    const float* src = col < 64 ? (Wq + col * 384)
                     : col < 128 ? (Wk + (col - 64) * 384)
                                 : (Wv + (col - 128) * 384);
    int kc = k >> 5, g = (k >> 3) & 3, kl = k & 7;
    Wp[kc * 6144 + (((g * 192 + col) ^ g) << 3) + kl] = (short)f2bf(src[k]);
}

// ---------------------------------------------------------------------------
// Fused kernel v11 = R19 v10 (barrier-free phase-1, W fully resident in LDS,
// x direct-to-reg triple-set) + HW v_cvt_pk_bf16_f32 for the A-frag build:
// the hand-rolled f2bf cost ~36 VALU per af (4 ops/element) on the critical
// dependent path; pkbf does it in 4 instructions with identical RNE
// rounding.  Everything else byte-identical to R19.
// ---------------------------------------------------------------------------
__global__ __launch_bounds__(1024) void fused_attn(
    const float* __restrict__ x, const short* __restrict__ Wp,
    float* __restrict__ out) {
    __shared__ short LDSH[73728];           // 147456 B
    short* const Wlds = LDSH;               // 12*6144 shorts (phase-1)
    short* const Ksh  = LDSH;               // [256*72]  (phase-2 overlay)
    short* const Vt   = LDSH + 18432;       // [64*264]
    short* const Pb   = LDSH + 35328;       // [16*640]

    const int tid = threadIdx.x;
    const int wv = tid >> 6, lane = tid & 63;
    const int g = lane >> 4, c = lane & 15;
    const int b = blockIdx.x;
    const int q0 = wv * 16;

    // direct x addressing: lane (g,c) of wave wv reads row q0+c, cols s*32+g*8
    const float* gxw = x + ((size_t)b * 256 + q0 + c) * 384 + g * 8;

    f32x4 acc[12];
#pragma unroll
    for (int j = 0; j < 12; ++j) acc[j] = (f32x4){0.f, 0.f, 0.f, 0.f};

    // ---- prologue: stage ALL of Wp (144 KB) into LDS; one barrier ----
#pragma unroll
    for (int r = 0; r < 9; ++r) {
        int seg = r * 16 + wv;              // 0..143 segments of 1 KB
        gload16(Wp + seg * 512 + lane * 8, Wlds + seg * 512);
    }
    __syncthreads();                        // drains gloads; Wlds visible

#define COMPUTE(S, F0, F1)                                                    \
    {                                                                         \
        const short* wb = Wlds + (S) * 6144;                                  \
        uint4 afu;                                                            \
        afu.x = pkbf((F0).x, (F0).y);                                         \
        afu.y = pkbf((F0).z, (F0).w);                                         \
        afu.z = pkbf((F1).x, (F1).y);                                         \
        afu.w = pkbf((F1).z, (F1).w);                                         \
        bf16x8 af = *(bf16x8*)&afu;                                           \
        _Pragma("unroll")                                                     \
        for (int h_ = 0; h_ < 2; ++h_) {                                      \
            bf16x8 bfr[6];                                                    \
            _Pragma("unroll")                                                 \
            for (int j6 = 0; j6 < 6; ++j6) {                                  \
                int col = (h_ * 6 + j6) * 16 + c;                             \
                bfr[j6] = *(const bf16x8*)&wb[((g * 192 + col) ^ g) << 3];    \
            }                                                                 \
            _Pragma("unroll")                                                 \
            for (int j6 = 0; j6 < 6; ++j6)                                    \
                acc[h_ * 6 + j6] = __builtin_amdgcn_mfma_f32_16x16x32_bf16(   \
                    af, bfr[j6], acc[h_ * 6 + j6], 0, 0, 0);                  \
        }                                                                     \
    }
// STEP(S): issue x(S+2) into LD set; compute S from CUR set.  Pure data
// flow -- no barriers, no asm waits; compiler pipelines, waves free-run.
#define STEP(S, LD0, LD1, CUR0, CUR1)                                        \
    {                                                                        \
        if ((S) <= 9) {                                                      \
            LD0 = *(const float4*)(gxw + ((S) + 2) * 32);                    \
            LD1 = *(const float4*)(gxw + ((S) + 2) * 32 + 4);                 \
        }                                                                    \
        COMPUTE(S, CUR0, CUR1)                                               \
    }

    float4 xA0, xA1, xB0, xB1, xC0, xC1;
    xA0 = *(const float4*)(gxw);
    xA1 = *(const float4*)(gxw + 4);
    xB0 = *(const float4*)(gxw + 32);
    xB1 = *(const float4*)(gxw + 36);

    STEP(0,  xC0, xC1, xA0, xA1)
    STEP(1,  xA0, xA1, xB0, xB1)
    STEP(2,  xB0, xB1, xC0, xC1)
    STEP(3,  xC0, xC1, xA0, xA1)
    STEP(4,  xA0, xA1, xB0, xB1)
    STEP(5,  xB0, xB1, xC0, xC1)
    STEP(6,  xC0, xC1, xA0, xA1)
    STEP(7,  xA0, xA1, xB0, xB1)
    STEP(8,  xB0, xB1, xC0, xC1)
    STEP(9,  xC0, xC1, xA0, xA1)
    STEP(10, xA0, xA1, xB0, xB1)
    COMPUTE(11, xC0, xC1)
    __syncthreads();                        // all Wlds reads done (overlay)

    // ---- epilogue (R19-verbatim): acc -> K/V LDS; Q -> regs via Pb.
    // C/D layout (verified): within 16x16 tile, col = c, row = 4g + r.
    short* const pbw = Pb + wv * 640;
    bf16x8 qf0, qf1;
    {
#pragma unroll
        for (int r = 0; r < 4; ++r) {
            pbw[(4 * g + r) * 40 + c]      = (short)f2bf(acc[0][r]);
            pbw[(4 * g + r) * 40 + 16 + c] = (short)f2bf(acc[1][r]);
        }
        qf0 = *(const bf16x8*)&pbw[c * 40 + g * 8];
#pragma unroll
        for (int r = 0; r < 4; ++r) {
            pbw[(4 * g + r) * 40 + c]      = (short)f2bf(acc[2][r]);
            pbw[(4 * g + r) * 40 + 16 + c] = (short)f2bf(acc[3][r]);
        }
        qf1 = *(const bf16x8*)&pbw[c * 40 + g * 8];
    }
#pragma unroll
    for (int nj = 4; nj < 8; ++nj) {
        const int row = q0 + 4 * g;
#pragma unroll
        for (int r = 0; r < 4; ++r)
            Ksh[(row + r) * 72 + (nj - 4) * 16 + c] = (short)f2bf(acc[nj][r]);
    }
#pragma unroll
    for (int nj = 8; nj < 12; ++nj) {
        const int h = (nj - 8) * 16 + c;
        const int swz = ((h >> 3) & 7) << 3;
        const int row = q0 + 4 * g;
#pragma unroll
        for (int r = 0; r < 4; ++r)
            Vt[(h * 264 + row + r) ^ swz] = (short)f2bf(acc[nj][r]);
    }
    __syncthreads();

    // ---------------- Phase 2: causal attention (R19-verbatim) --------------
    {
        f32x4 o[4];
#pragma unroll
        for (int nj = 0; nj < 4; ++nj) o[nj] = (f32x4){0.f, 0.f, 0.f, 0.f};
        float m[4] = {-INFINITY, -INFINITY, -INFINITY, -INFINITY};
        float ls[4] = {0.f, 0.f, 0.f, 0.f};
        const int jmax = (q0 + 15) >> 5;

        for (int j = 0; j <= jmax; ++j) {
            f32x4 s0 = {0.f, 0.f, 0.f, 0.f}, s1 = {0.f, 0.f, 0.f, 0.f};
            {
                bf16x8 kf;
                kf = *(const bf16x8*)&Ksh[(32 * j + c) * 72 + g * 8];
                s0 = __builtin_amdgcn_mfma_f32_16x16x32_bf16(qf0, kf, s0, 0, 0, 0);
                kf = *(const bf16x8*)&Ksh[(32 * j + c) * 72 + 32 + g * 8];
                s0 = __builtin_amdgcn_mfma_f32_16x16x32_bf16(qf1, kf, s0, 0, 0, 0);
                kf = *(const bf16x8*)&Ksh[(32 * j + 16 + c) * 72 + g * 8];
                s1 = __builtin_amdgcn_mfma_f32_16x16x32_bf16(qf0, kf, s1, 0, 0, 0);
                kf = *(const bf16x8*)&Ksh[(32 * j + 16 + c) * 72 + 32 + g * 8];
                s1 = __builtin_amdgcn_mfma_f32_16x16x32_bf16(qf1, kf, s1, 0, 0, 0);
            }
            float t0[4], t1[4];
#pragma unroll
            for (int r = 0; r < 4; ++r) {
                t0[r] = s0[r] * 0.125f;
                t1[r] = s1[r] * 0.125f;
            }
            if (j == jmax) {   // wave-uniform: diagonal tile, causal mask
                int q = q0 + 4 * g;
#pragma unroll
                for (int r = 0; r < 4; ++r) {
                    if (32 * j + c > q + r) t0[r] = -INFINITY;
                    if (32 * j + 16 + c > q + r) t1[r] = -INFINITY;
                }
            }
            float corr[4], p0[4], p1[4];
#pragma unroll
            for (int r = 0; r < 4; ++r) {
                float v = fmaxf(t0[r], t1[r]);
#pragma unroll
                for (int off = 1; off < 16; off <<= 1) v = fmaxf(v, __shfl_xor(v, off, 16));
                float mn = fmaxf(m[r], v);
                corr[r] = __expf(m[r] - mn);   // first tile: exp(-inf)=0
                m[r] = mn;
                p0[r] = __expf(t0[r] - mn);
                p1[r] = __expf(t1[r] - mn);
                float rs = p0[r] + p1[r];
#pragma unroll
                for (int off = 1; off < 16; off <<= 1) rs += __shfl_xor(rs, off, 16);
                ls[r] = ls[r] * corr[r] + rs;
            }
#pragma unroll
            for (int nj = 0; nj < 4; ++nj) {
                f32x4 t = o[nj];
                t[0] *= corr[0]; t[1] *= corr[1]; t[2] *= corr[2]; t[3] *= corr[3];
                o[nj] = t;
            }
            // P -> Pb (C/D rows) -> A-frag read (same-wave RAW, in-order LDS)
#pragma unroll
            for (int r = 0; r < 4; ++r) {
                pbw[(4 * g + r) * 40 + c]      = (short)f2bf(p0[r]);
                pbw[(4 * g + r) * 40 + 16 + c] = (short)f2bf(p1[r]);
            }
            bf16x8 pfa = *(const bf16x8*)&pbw[c * 40 + g * 8];
#pragma unroll
            for (int nj = 0; nj < 4; ++nj) {
                int h = 16 * nj + c;
                int swz = ((2 * nj + (c >> 3)) & 7) << 3;
                bf16x8 vf = *(const bf16x8*)&Vt[(h * 264 + 32 * j + g * 8) ^ swz];
                o[nj] = __builtin_amdgcn_mfma_f32_16x16x32_bf16(pfa, vf, o[nj], 0, 0, 0);
            }
        }
        float inv[4];
#pragma unroll
        for (int r = 0; r < 4; ++r) inv[r] = 1.f / ls[r];
        float* ob = out + ((size_t)b * 256 + q0) * 64;
#pragma unroll
        for (int nj = 0; nj < 4; ++nj)
#pragma unroll
            for (int r = 0; r < 4; ++r)
                ob[(4 * g + r) * 64 + 16 * nj + c] = o[nj][r] * inv[r];
    }
#undef COMPUTE
#undef STEP
}

// ---------------------------------------------------------------------------
extern "C" void kernel_launch(void* const* d_in, const int* in_sizes, int n_in,
                              void* d_out, int out_size, void* d_ws, size_t ws_size,
                              hipStream_t stream) {
    const float* x  = (const float*)d_in[0];
    const float* Wq = (const float*)d_in[1];
    const float* Wk = (const float*)d_in[2];
    const float* Wv = (const float*)d_in[3];
    float* out = (float*)d_out;

    short* Wp = (short*)d_ws;   // 73728 shorts (144 KB)

    wconv<<<dim3(288), dim3(256), 0, stream>>>(Wq, Wk, Wv, Wp);
    fused_attn<<<dim3(256), dim3(1024), 0, stream>>>(x, Wp, out);
}